// Round 22
// baseline (300.142 us; speedup 1.0000x reference)
//
#include <hip/hip_runtime.h>
#include <hip/hip_cooperative_groups.h>

namespace cg = cooperative_groups;

#define NN 50000
#define NE 640000
#define NR 3
#define DH 128
#define ET (NR * NE)           // 1,920,000 edges total

#define BK 256                 // nodes per bucket
#define NBK 196                // buckets per relation
#define NBT (NR * NBK)         // 588 buckets
#define NCH 512                // edge chunks
#define CH (ET / NCH)          // 3750 edges per chunk (exact)
#define CAPB 4096              // fixed bucket capacity (mean 3265, sigma 57 -> 14 sigma)

typedef __attribute__((ext_vector_type(8))) short short8;
typedef __attribute__((ext_vector_type(4))) float f32x4;
typedef __attribute__((ext_vector_type(2))) float f32x2;

__device__ __forceinline__ float bf2f(uint u) { return __uint_as_float(u << 16); }
__device__ __forceinline__ uint f2bf(float f) {
    uint u = __float_as_uint(f);
    u += 0x7fff + ((u >> 16) & 1);  // round-to-nearest-even
    return u >> 16;
}
__device__ __forceinline__ uint pack2(float a, float b) { return f2bf(a) | (f2bf(b) << 16); }
// truncating bf16 pair pack: one v_perm. EXACT for fp8-derived values
// (e4m3 has 3 mantissa bits, bf16 has 8 -> no rounding error).
__device__ __forceinline__ uint pk2t(float a, float b) {
    return __builtin_amdgcn_perm(__float_as_uint(b), __float_as_uint(a), 0x07060302u);
}
__device__ __forceinline__ f32x2 pkadd(f32x2 a, f32x2 b) {
    f32x2 d;
    asm("v_pk_add_f32 %0, %1, %2" : "=v"(d) : "v"(a), "v"(b));
    return d;
}
// fp8 e4m3 (OCP) HW converts
__device__ __forceinline__ f32x2 f8lo(uint u) {
    return __builtin_amdgcn_cvt_pk_f32_fp8(u, false);
}
__device__ __forceinline__ f32x2 f8hi(uint u) {
    return __builtin_amdgcn_cvt_pk_f32_fp8(u, true);
}
__device__ __forceinline__ uint pack4f8(float a, float b, float c, float d) {
    int w = __builtin_amdgcn_cvt_pk_fp8_f32(a, b, 0, false);
    w = __builtin_amdgcn_cvt_pk_fp8_f32(c, d, w, true);
    return (uint)w;
}

// ---------------- fused first wave: per-chunk histogram + conv(x->fp8) + wpack + bias
__global__ __launch_bounds__(256) void prep_hist(const float* __restrict__ x,
                                                 const int* __restrict__ ei,
                                                 const float* __restrict__ Wn,
                                                 const float* __restrict__ Wr,
                                                 const float* __restrict__ bc,
                                                 const float* __restrict__ linW,
                                                 unsigned char* __restrict__ xf8,
                                                 ushort* __restrict__ Wpack,
                                                 float* __restrict__ bsum,
                                                 int* __restrict__ gcnt) {
    int bid = blockIdx.x;
    int t = threadIdx.x;
    if (bid < NCH) {  // histogram chunk
        __shared__ int hist[NBT];
        for (int i = t; i < NBT; i += 256) hist[i] = 0;
        __syncthreads();
        int e0 = bid * CH;
        for (int i = t; i < CH; i += 256) {
            int e = e0 + i;
            int r = (e >= 2 * NE) ? 2 : (e >= NE ? 1 : 0);
            int le = e - r * NE;
            int dst = ei[r * 2 * NE + NE + le];
            atomicAdd(&hist[r * NBK + (dst >> 8)], 1);
        }
        __syncthreads();
        for (int i = t; i < NBT; i += 256) gcnt[bid * NBT + i] = hist[i];
    } else if (bid < NCH + 6251) {  // conv: NN*DH/4 float4s -> 4x fp8 each
        int gid = (bid - NCH) * 256 + t;
        if (gid >= NN * DH / 4) return;
        float4 v = ((const float4*)x)[gid];
        ((uint*)xf8)[gid] = pack4f8(v.x, v.y, v.z, v.w);
    } else if (bid < NCH + 6251 + 66) {  // weight pack: 264 frags x 64 lanes
        int tid = (bid - NCH - 6251) * 256 + t;
        if (tid >= 264 * 64) return;
        int f = tid >> 6, lane = tid & 63;
        int l15 = lane & 15, l4 = lane >> 4;
        ushort hi8[8], lo8[8];
        if (f < 256) {
            int layer = f >> 7, seg = (f >> 5) & 3, kc = (f >> 3) & 3, nb = f & 7;
            int col = nb * 16 + l15;
            int kb = kc * 32 + l4 * 8;
#pragma unroll
            for (int e = 0; e < 8; ++e) {
                int k = kb + e;
                float v;
                if (seg < 3) {
                    v = Wn[(((size_t)layer * 3 + seg) * 128 + k) * 128 + col];
                } else {
                    const float* base = Wr + (size_t)layer * 3 * 16384;
                    v = base[k * 128 + col] + base[16384 + k * 128 + col] +
                        base[32768 + k * 128 + col];
                }
                uint h = f2bf(v);
                float rem = v - bf2f(h);
                hi8[e] = (ushort)h;
                lo8[e] = (ushort)f2bf(rem);
            }
        } else {
            int g = f - 256;
            int kc = g >> 1, nb = g & 1;
            int col = nb * 16 + l15;
            int kb = kc * 32 + l4 * 8;
#pragma unroll
            for (int e = 0; e < 8; ++e) {
                float v = linW[(kb + e) * 32 + col];
                uint h = f2bf(v);
                float rem = v - bf2f(h);
                hi8[e] = (ushort)h;
                lo8[e] = (ushort)f2bf(rem);
            }
        }
        *(short8*)(Wpack + (size_t)f * 1024 + lane * 8) = *(short8*)hi8;
        *(short8*)(Wpack + (size_t)f * 1024 + 512 + lane * 8) = *(short8*)lo8;
    } else {  // bias sum: 2 layers x 128
        int l = t >> 7, j = t & 127;
        const float* bb = bc + l * 3 * DH;
        bsum[t] = bb[j] + bb[DH + j] + bb[2 * DH + j];
    }
}

// ---------------- cooperative build: cscan -> scatter -> csr (588 blocks, all co-resident)
// Each phase runs at its natural standalone parallelism (no compression; r8's
// failure mode was squeezing a 6318-block phase into 512 blocks — not done here).
__global__ __launch_bounds__(256) void build_csr(const int* __restrict__ ei,
                                                 const int* __restrict__ gcnt,
                                                 int* __restrict__ gbase,
                                                 int* __restrict__ btot,
                                                 uint* __restrict__ pairs,
                                                 int* __restrict__ csr,
                                                 int2* __restrict__ od) {
    cg::grid_group grid = cg::this_grid();
    const int b = blockIdx.x, t = threadIdx.x;
    const int lane = t & 63, w = t >> 6;
    __shared__ int sm[NBT];   // phase B cursors
    __shared__ int sh[BK];    // phase C hist
    __shared__ int sc2[BK];   // phase C cursors
    __shared__ int ws[4];

    // ---- phase A: per-bucket scan over 512 chunk counts (1 block : 1 bucket) ----
    {
        int v0 = gcnt[(2 * t) * NBT + b];
        int v1 = gcnt[(2 * t + 1) * NBT + b];
        int s = v0 + v1;
        int sc = s;
#pragma unroll
        for (int d = 1; d < 64; d <<= 1) {
            int u = __shfl_up(sc, d);
            if (lane >= d) sc += u;
        }
        if (lane == 63) ws[w] = sc;
        __syncthreads();
        int add = 0;
#pragma unroll
        for (int q = 0; q < 3; ++q)
            if (q < w) add += ws[q];
        int incl = sc + add;
        int excl = incl - s;
        gbase[(2 * t) * NBT + b] = excl;
        gbase[(2 * t + 1) * NBT + b] = excl + v0;
        if (t == 255) btot[b] = incl;
    }
    grid.sync();

    // ---- phase B: scatter pairs via LDS cursors (blocks 0..511) ----
    if (b < NCH) {
        for (int i = t; i < NBT; i += 256) sm[i] = i * CAPB + gbase[b * NBT + i];
        __syncthreads();
        int e0 = b * CH;
        for (int i = t; i < CH; i += 256) {
            int e = e0 + i;
            int r = (e >= 2 * NE) ? 2 : (e >= NE ? 1 : 0);
            int le = e - r * NE;
            int src = ei[r * 2 * NE + le];
            int dst = ei[r * 2 * NE + NE + le];
            int bk = r * NBK + (dst >> 8);
            int pos = atomicAdd(&sm[bk], 1);
            pairs[pos] = ((uint)src << 8) | (uint)(dst & 255u);
        }
    }
    grid.sync();

    // ---- phase C: per-bucket hist + scan + scatter; writes od ----
    {
        int r = b / NBK;
        int n0 = (b - r * NBK) * BK;
        int cnt = btot[b];
        int base = b * CAPB;
        sh[t] = 0;
        __syncthreads();
        const uint* pp = pairs + base;
        for (int i = t; i < cnt; i += 256) atomicAdd(&sh[pp[i] & 255u], 1);
        __syncthreads();
        int v = sh[t], s = v;
#pragma unroll
        for (int d = 1; d < 64; d <<= 1) {
            int u = __shfl_up(s, d);
            if (lane >= d) s += u;
        }
        if (lane == 63) ws[w] = s;
        __syncthreads();
        int add = 0;
#pragma unroll
        for (int q = 0; q < 3; ++q)
            if (q < w) add += ws[q];
        int excl = s + add - v;
        int node = n0 + t;
        if (node < NN) od[r * NN + node] = make_int2(base + excl, v);
        sc2[t] = excl;
        __syncthreads();
        for (int i = t; i < cnt; i += 256) {
            uint pk = pp[i];
            int pos = atomicAdd(&sc2[pk & 255u], 1);
            csr[base + pos] = (int)(pk >> 8);
        }
    }
}

// ---------------- aggregation: one 8-lane group per (rel,node), fp8 gather, fp8 means ----------------
__global__ __launch_bounds__(256) void aggr_kernel(const unsigned char* __restrict__ tb8,
                                                   unsigned char* __restrict__ mean8,
                                                   const int* __restrict__ csr,
                                                   const int2* __restrict__ od) {
    int gtask = (blockIdx.x * 256 + threadIdx.x) >> 3;  // (rel,node) per 8-lane group
    if (gtask >= NR * NN) return;
    int cs = threadIdx.x & 7;
    int2 v2 = od[gtask];
    int base = v2.x, d = v2.y;
    const int* lst = csr + base;
    const unsigned char* tbc = tb8 + cs * 16;

    f32x2 a2[8] = {{0.f, 0.f}, {0.f, 0.f}, {0.f, 0.f}, {0.f, 0.f},
                   {0.f, 0.f}, {0.f, 0.f}, {0.f, 0.f}, {0.f, 0.f}};
    for (int e = 0; e < d; e += 8) {
        uint4 q[8];
#pragma unroll
        for (int k = 0; k < 8; ++k) {
            int ee = e + k;
            int idx = lst[min(ee, d - 1)];
            uint4 v = *(const uint4*)(tbc + (size_t)idx * DH);
            bool ok = ee < d;
            q[k].x = ok ? v.x : 0u;  // fp8 0x00 == +0.0 -> exact no-op add
            q[k].y = ok ? v.y : 0u;
            q[k].z = ok ? v.z : 0u;
            q[k].w = ok ? v.w : 0u;
        }
#pragma unroll
        for (int k = 0; k < 8; ++k) {
            a2[0] = pkadd(a2[0], f8lo(q[k].x));
            a2[1] = pkadd(a2[1], f8hi(q[k].x));
            a2[2] = pkadd(a2[2], f8lo(q[k].y));
            a2[3] = pkadd(a2[3], f8hi(q[k].y));
            a2[4] = pkadd(a2[4], f8lo(q[k].z));
            a2[5] = pkadd(a2[5], f8hi(q[k].z));
            a2[6] = pkadd(a2[6], f8lo(q[k].w));
            a2[7] = pkadd(a2[7], f8hi(q[k].w));
        }
    }
    float inv = 1.f / fmaxf((float)d, 1.f);
    uint4 o;
    o.x = pack4f8(a2[0].x * inv, a2[0].y * inv, a2[1].x * inv, a2[1].y * inv);
    o.y = pack4f8(a2[2].x * inv, a2[2].y * inv, a2[3].x * inv, a2[3].y * inv);
    o.z = pack4f8(a2[4].x * inv, a2[4].y * inv, a2[5].x * inv, a2[5].y * inv);
    o.w = pack4f8(a2[6].x * inv, a2[6].y * inv, a2[7].x * inv, a2[7].y * inv);
    *(uint4*)(mean8 + (size_t)gtask * DH + cs * 16) = o;
}

// ---------------- MFMA GEMM: 64x128 tile, K=512, swapped-operand ----------------
template <bool LAST>
__global__ __launch_bounds__(256) void gemm_mfma(
    const float* __restrict__ xroot,        // fp32 x (LAST=false)
    const ushort* __restrict__ tbroot,      // bf16 h1b (LAST=true)
    const unsigned char* __restrict__ mean8,// [3][NN][128] fp8 means
    void* __restrict__ h_out,
    unsigned char* __restrict__ h1f8,       // fp8 h1 table out (LAST=false)
    const ushort* __restrict__ Wp,
    const float* __restrict__ bsum,
    const ushort* __restrict__ lWp,
    const float* __restrict__ linb)
{
    __shared__ ushort As[64][136];

    const int t = threadIdx.x, lane = t & 63, w = t >> 6;
    const int l15 = lane & 15, l4 = lane >> 4;
    const int row0 = blockIdx.x * 64;

    f32x4 acc[4][2];
    {
        float4 b0 = *(const float4*)(bsum + (2 * w) * 16 + l4 * 4);
        float4 b1 = *(const float4*)(bsum + (2 * w + 1) * 16 + l4 * 4);
#pragma unroll
        for (int rt = 0; rt < 4; ++rt) {
            acc[rt][0] = f32x4{b0.x, b0.y, b0.z, b0.w};
            acc[rt][1] = f32x4{b1.x, b1.y, b1.z, b1.w};
        }
    }

    for (int seg = 0; seg < 4; ++seg) {
        __syncthreads();
        if (seg < NR) {
            // stage fp8 means: 64 rows x 8 chunks of 16 fp8; 256 threads x 2 iters
#pragma unroll
            for (int i = 0; i < 2; ++i) {
                int q = i * 256 + t;
                int r = q >> 3, c = q & 7;
                int node = row0 + r;
                uint4 o0 = make_uint4(0, 0, 0, 0), o1 = make_uint4(0, 0, 0, 0);
                if (node < NN) {
                    uint4 v = *(const uint4*)(mean8 + ((size_t)seg * NN + node) * DH + c * 16);
                    f32x2 lo, hi;
                    lo = f8lo(v.x); hi = f8hi(v.x);
                    o0.x = pk2t(lo.x, lo.y); o0.y = pk2t(hi.x, hi.y);
                    lo = f8lo(v.y); hi = f8hi(v.y);
                    o0.z = pk2t(lo.x, lo.y); o0.w = pk2t(hi.x, hi.y);
                    lo = f8lo(v.z); hi = f8hi(v.z);
                    o1.x = pk2t(lo.x, lo.y); o1.y = pk2t(hi.x, hi.y);
                    lo = f8lo(v.w); hi = f8hi(v.w);
                    o1.z = pk2t(lo.x, lo.y); o1.w = pk2t(hi.x, hi.y);
                }
                *(uint4*)(&As[r][c * 16]) = o0;
                *(uint4*)(&As[r][c * 16 + 8]) = o1;
            }
        } else {
            // root segment: 64 rows x 16 chunks of 8 bf16; 256 threads x 4 iters
#pragma unroll
            for (int i = 0; i < 4; ++i) {
                int q = i * 256 + t;
                int r = q >> 4, c = q & 15;
                int node = row0 + r;
                uint4 v = make_uint4(0, 0, 0, 0);
                if (node < NN) {
                    if constexpr (!LAST) {
                        float4 f0 = *(const float4*)(xroot + (size_t)node * DH + c * 8);
                        float4 f1 = *(const float4*)(xroot + (size_t)node * DH + c * 8 + 4);
                        v.x = pack2(f0.x, f0.y);
                        v.y = pack2(f0.z, f0.w);
                        v.z = pack2(f1.x, f1.y);
                        v.w = pack2(f1.z, f1.w);
                    } else {
                        v = *(const uint4*)(tbroot + (size_t)node * DH + c * 8);
                    }
                }
                *(uint4*)(&As[r][c * 8]) = v;
            }
        }
        __syncthreads();
        const ushort* wseg = Wp + (size_t)seg * 32768;
#pragma unroll
        for (int kc = 0; kc < 4; ++kc) {
            const ushort* wkc = wseg + kc * 8192;
            short8 bh0 = *(const short8*)(wkc + (2 * w) * 1024 + lane * 8);
            short8 bl0 = *(const short8*)(wkc + (2 * w) * 1024 + 512 + lane * 8);
            short8 bh1 = *(const short8*)(wkc + (2 * w + 1) * 1024 + lane * 8);
            short8 bl1 = *(const short8*)(wkc + (2 * w + 1) * 1024 + 512 + lane * 8);
#pragma unroll
            for (int rt = 0; rt < 4; ++rt) {
                short8 a = *(const short8*)(&As[rt * 16 + l15][kc * 32 + l4 * 8]);
                acc[rt][0] = __builtin_amdgcn_mfma_f32_16x16x32_bf16(bh0, a, acc[rt][0], 0, 0, 0);
                acc[rt][0] = __builtin_amdgcn_mfma_f32_16x16x32_bf16(bl0, a, acc[rt][0], 0, 0, 0);
                acc[rt][1] = __builtin_amdgcn_mfma_f32_16x16x32_bf16(bh1, a, acc[rt][1], 0, 0, 0);
                acc[rt][1] = __builtin_amdgcn_mfma_f32_16x16x32_bf16(bl1, a, acc[rt][1], 0, 0, 0);
            }
        }
    }

    if constexpr (!LAST) {
        ushort* hb = (ushort*)h_out;
#pragma unroll
        for (int rt = 0; rt < 4; ++rt) {
            int node = row0 + rt * 16 + l15;
            if (node < NN) {
#pragma unroll
                for (int j = 0; j < 2; ++j) {
                    int c0 = (2 * w + j) * 16 + l4 * 4;
                    float r0 = fmaxf(acc[rt][j][0], 0.f);
                    float r1 = fmaxf(acc[rt][j][1], 0.f);
                    float r2 = fmaxf(acc[rt][j][2], 0.f);
                    float r3 = fmaxf(acc[rt][j][3], 0.f);
                    uint2 o;
                    o.x = pack2(r0, r1);
                    o.y = pack2(r2, r3);
                    *(uint2*)(hb + (size_t)node * DH + c0) = o;
                    *(uint*)(h1f8 + (size_t)node * DH + c0) = pack4f8(r0, r1, r2, r3);
                }
            }
        }
    } else {
        __syncthreads();
#pragma unroll
        for (int rt = 0; rt < 4; ++rt) {
            int rl = rt * 16 + l15;
#pragma unroll
            for (int j = 0; j < 2; ++j) {
                int c0 = (2 * w + j) * 16 + l4 * 4;
                uint2 o;
                o.x = pack2(fmaxf(acc[rt][j][0], 0.f), fmaxf(acc[rt][j][1], 0.f));
                o.y = pack2(fmaxf(acc[rt][j][2], 0.f), fmaxf(acc[rt][j][3], 0.f));
                *(uint2*)(&As[rl][c0]) = o;
            }
        }
        __syncthreads();
        f32x4 acc2[2];
        {
            float4 c0 = *(const float4*)(linb + l4 * 4);
            float4 c1 = *(const float4*)(linb + 16 + l4 * 4);
            acc2[0] = f32x4{c0.x, c0.y, c0.z, c0.w};
            acc2[1] = f32x4{c1.x, c1.y, c1.z, c1.w};
        }
#pragma unroll
        for (int kc = 0; kc < 4; ++kc) {
            short8 a = *(const short8*)(&As[w * 16 + l15][kc * 32 + l4 * 8]);
#pragma unroll
            for (int j = 0; j < 2; ++j) {
                short8 bh = *(const short8*)(lWp + (kc * 2 + j) * 1024 + lane * 8);
                short8 bl = *(const short8*)(lWp + (kc * 2 + j) * 1024 + 512 + lane * 8);
                acc2[j] = __builtin_amdgcn_mfma_f32_16x16x32_bf16(bh, a, acc2[j], 0, 0, 0);
                acc2[j] = __builtin_amdgcn_mfma_f32_16x16x32_bf16(bl, a, acc2[j], 0, 0, 0);
            }
        }
        float* outp = (float*)h_out;
        int node = row0 + w * 16 + l15;
        if (node < NN) {
#pragma unroll
            for (int j = 0; j < 2; ++j) {
                *(f32x4*)(outp + (size_t)node * 32 + j * 16 + l4 * 4) = acc2[j];
            }
        }
    }
}

extern "C" void kernel_launch(void* const* d_in, const int* in_sizes, int n_in,
                              void* d_out, int out_size, void* d_ws, size_t ws_size,
                              hipStream_t stream) {
    const float* x = (const float*)d_in[0];
    const int* ei = (const int*)d_in[1];
    const float* Wn = (const float*)d_in[2];
    const float* Wr = (const float*)d_in[3];
    const float* bc = (const float*)d_in[4];
    const float* linW = (const float*)d_in[5];
    const float* linb = (const float*)d_in[6];
    float* out = (float*)d_out;

    char* p = (char*)d_ws;
    int* gcnt = (int*)p;     p += (size_t)NCH * NBT * 4;      // 1.2 MB
    int* gbase = (int*)p;    p += (size_t)NCH * NBT * 4;      // 1.2 MB
    int* btot = (int*)p;     p += 4096;
    int2* od = (int2*)p;     p += (size_t)NR * NN * 8;        // 1.2 MB
    int* csr = (int*)p;      p += (size_t)NBT * CAPB * 4;     // 9.6 MB
    ushort* Wpack = (ushort*)p; p += (size_t)264 * 1024 * 2;  // 540 KB
    float* bsum = (float*)p; p += 4096;
    unsigned char* f8tab = (unsigned char*)p; p += (size_t)NN * DH;  // 6.4 MB (x-fp8, then h1-fp8)
    ushort* h1b = (ushort*)p; p += (size_t)NN * DH * 2;       // 12.8 MB
    unsigned char* mean8 = (unsigned char*)p; p += (size_t)NR * NN * DH;  // 19.2 MB
    uint* pairs = (uint*)mean8;  // alias (7.7 MB): consumed by build_csr
                                 // before any aggr writes mean8

    prep_hist<<<NCH + 6251 + 66 + 1, 256, 0, stream>>>(x, ei, Wn, Wr, bc, linW,
                                                       f8tab, Wpack, bsum, gcnt);
    {
        void* args[] = {(void*)&ei,   (void*)&gcnt, (void*)&gbase, (void*)&btot,
                        (void*)&pairs,(void*)&csr,  (void*)&od};
        hipLaunchCooperativeKernel((void*)build_csr, dim3(NBT), dim3(256), args, 0, stream);
    }

    int lb = (NN + 63) / 64;              // 782
    int ag = (NR * NN * 8 + 255) / 256;   // 4688 blocks (8 lanes per task)

    // layer 1: gather from x-fp8, root from x-fp32; writes h1b + h1-fp8 (into f8tab)
    aggr_kernel<<<ag, 256, 0, stream>>>(f8tab, mean8, csr, od);
    gemm_mfma<false><<<lb, 256, 0, stream>>>(x, nullptr, mean8, h1b, f8tab,
                                             Wpack, bsum, nullptr, nullptr);
    // layer 2: gather from h1-fp8, root from h1b; fused final linear
    aggr_kernel<<<ag, 256, 0, stream>>>(f8tab, mean8, csr, od);
    gemm_mfma<true><<<lb, 256, 0, stream>>>(nullptr, h1b, mean8, out, nullptr,
                                            Wpack + (size_t)128 * 1024, bsum + DH,
                                            Wpack + (size_t)256 * 1024, linb);
}

// Round 23
// 153.089 us; speedup vs baseline: 1.9606x; 1.9606x over previous
//
#include <hip/hip_runtime.h>

#define NN 50000
#define NE 640000
#define NR 3
#define DH 128
#define ET (NR * NE)           // 1,920,000 edges total

#define BK 256                 // nodes per bucket
#define NBK 196                // buckets per relation
#define NBT (NR * NBK)         // 588 buckets
#define NCH 512                // edge chunks
#define CH (ET / NCH)          // 3750 edges per chunk (exact)
#define CAPB 4096              // fixed bucket capacity (mean 3265, sigma 57 -> 14 sigma)

typedef __attribute__((ext_vector_type(8))) short short8;
typedef __attribute__((ext_vector_type(4))) float f32x4;
typedef __attribute__((ext_vector_type(2))) float f32x2;

__device__ __forceinline__ float bf2f(uint u) { return __uint_as_float(u << 16); }
__device__ __forceinline__ uint f2bf(float f) {
    uint u = __float_as_uint(f);
    u += 0x7fff + ((u >> 16) & 1);  // round-to-nearest-even
    return u >> 16;
}
__device__ __forceinline__ uint pack2(float a, float b) { return f2bf(a) | (f2bf(b) << 16); }
// truncating bf16 pair pack: one v_perm. EXACT for fp8-derived values
// (e4m3 has 3 mantissa bits, bf16 has 8 -> no rounding error).
__device__ __forceinline__ uint pk2t(float a, float b) {
    return __builtin_amdgcn_perm(__float_as_uint(b), __float_as_uint(a), 0x07060302u);
}
__device__ __forceinline__ f32x2 pkadd(f32x2 a, f32x2 b) {
    f32x2 d;
    asm("v_pk_add_f32 %0, %1, %2" : "=v"(d) : "v"(a), "v"(b));
    return d;
}
// fp8 e4m3 (OCP) HW converts
__device__ __forceinline__ f32x2 f8lo(uint u) {
    return __builtin_amdgcn_cvt_pk_f32_fp8(u, false);
}
__device__ __forceinline__ f32x2 f8hi(uint u) {
    return __builtin_amdgcn_cvt_pk_f32_fp8(u, true);
}
__device__ __forceinline__ uint pack4f8(float a, float b, float c, float d) {
    int w = __builtin_amdgcn_cvt_pk_fp8_f32(a, b, 0, false);
    w = __builtin_amdgcn_cvt_pk_fp8_f32(c, d, w, true);
    return (uint)w;
}

// ---------------- fused first wave: per-chunk histogram + conv(x->fp8) + wpack + bias
__global__ __launch_bounds__(256) void prep_hist(const float* __restrict__ x,
                                                 const int* __restrict__ ei,
                                                 const float* __restrict__ Wn,
                                                 const float* __restrict__ Wr,
                                                 const float* __restrict__ bc,
                                                 const float* __restrict__ linW,
                                                 unsigned char* __restrict__ xf8,
                                                 ushort* __restrict__ Wpack,
                                                 float* __restrict__ bsum,
                                                 int* __restrict__ gcnt) {
    int bid = blockIdx.x;
    int t = threadIdx.x;
    if (bid < NCH) {  // histogram chunk
        __shared__ int hist[NBT];
        for (int i = t; i < NBT; i += 256) hist[i] = 0;
        __syncthreads();
        int e0 = bid * CH;
        for (int i = t; i < CH; i += 256) {
            int e = e0 + i;
            int r = (e >= 2 * NE) ? 2 : (e >= NE ? 1 : 0);
            int le = e - r * NE;
            int dst = ei[r * 2 * NE + NE + le];
            atomicAdd(&hist[r * NBK + (dst >> 8)], 1);
        }
        __syncthreads();
        for (int i = t; i < NBT; i += 256) gcnt[bid * NBT + i] = hist[i];
    } else if (bid < NCH + 6251) {  // conv: NN*DH/4 float4s -> 4x fp8 each
        int gid = (bid - NCH) * 256 + t;
        if (gid >= NN * DH / 4) return;
        float4 v = ((const float4*)x)[gid];
        ((uint*)xf8)[gid] = pack4f8(v.x, v.y, v.z, v.w);
    } else if (bid < NCH + 6251 + 66) {  // weight pack: 264 frags x 64 lanes
        int tid = (bid - NCH - 6251) * 256 + t;
        if (tid >= 264 * 64) return;
        int f = tid >> 6, lane = tid & 63;
        int l15 = lane & 15, l4 = lane >> 4;
        ushort hi8[8], lo8[8];
        if (f < 256) {
            int layer = f >> 7, seg = (f >> 5) & 3, kc = (f >> 3) & 3, nb = f & 7;
            int col = nb * 16 + l15;
            int kb = kc * 32 + l4 * 8;
#pragma unroll
            for (int e = 0; e < 8; ++e) {
                int k = kb + e;
                float v;
                if (seg < 3) {
                    v = Wn[(((size_t)layer * 3 + seg) * 128 + k) * 128 + col];
                } else {
                    const float* base = Wr + (size_t)layer * 3 * 16384;
                    v = base[k * 128 + col] + base[16384 + k * 128 + col] +
                        base[32768 + k * 128 + col];
                }
                uint h = f2bf(v);
                float rem = v - bf2f(h);
                hi8[e] = (ushort)h;
                lo8[e] = (ushort)f2bf(rem);
            }
        } else {
            int g = f - 256;
            int kc = g >> 1, nb = g & 1;
            int col = nb * 16 + l15;
            int kb = kc * 32 + l4 * 8;
#pragma unroll
            for (int e = 0; e < 8; ++e) {
                float v = linW[(kb + e) * 32 + col];
                uint h = f2bf(v);
                float rem = v - bf2f(h);
                hi8[e] = (ushort)h;
                lo8[e] = (ushort)f2bf(rem);
            }
        }
        *(short8*)(Wpack + (size_t)f * 1024 + lane * 8) = *(short8*)hi8;
        *(short8*)(Wpack + (size_t)f * 1024 + 512 + lane * 8) = *(short8*)lo8;
    } else {  // bias sum: 2 layers x 128
        int l = t >> 7, j = t & 127;
        const float* bb = bc + l * 3 * DH;
        bsum[t] = bb[j] + bb[DH + j] + bb[2 * DH + j];
    }
}

// ---------------- pass 2: per-bucket scan over chunk counts (bases fixed b*CAPB) ----------------
__global__ __launch_bounds__(256) void cscan_kernel(const int* __restrict__ gcnt,
                                                    int* __restrict__ gbase,
                                                    int* __restrict__ btot) {
    int b = blockIdx.x, t = threadIdx.x;  // 512 values, 2 per thread
    int v0 = gcnt[(2 * t) * NBT + b];
    int v1 = gcnt[(2 * t + 1) * NBT + b];
    int s = v0 + v1;
    int lane = t & 63, w = t >> 6;
    int sc = s;
#pragma unroll
    for (int d = 1; d < 64; d <<= 1) {
        int u = __shfl_up(sc, d);
        if (lane >= d) sc += u;
    }
    __shared__ int ws[4];
    if (lane == 63) ws[w] = sc;
    __syncthreads();
    int add = 0;
#pragma unroll
    for (int q = 0; q < 3; ++q)
        if (q < w) add += ws[q];
    int incl = sc + add;
    int excl = incl - s;
    gbase[(2 * t) * NBT + b] = excl;
    gbase[(2 * t + 1) * NBT + b] = excl + v0;
    if (t == 255) btot[b] = incl;
}

// ---------------- pass 3: scatter pairs via LDS cursors (no global atomics) ----------------
__global__ __launch_bounds__(256) void scatter_kernel(const int* __restrict__ ei,
                                                      const int* __restrict__ gbase,
                                                      uint* __restrict__ pairs) {
    __shared__ int cur[NBT];
    int g = blockIdx.x, t = threadIdx.x;
    for (int i = t; i < NBT; i += 256) cur[i] = i * CAPB + gbase[g * NBT + i];
    __syncthreads();
    int e0 = g * CH;
    for (int i = t; i < CH; i += 256) {
        int e = e0 + i;
        int r = (e >= 2 * NE) ? 2 : (e >= NE ? 1 : 0);
        int le = e - r * NE;
        int src = ei[r * 2 * NE + le];
        int dst = ei[r * 2 * NE + NE + le];
        int b = r * NBK + (dst >> 8);
        int pos = atomicAdd(&cur[b], 1);
        pairs[pos] = ((uint)src << 8) | (uint)(dst & 255u);
    }
}

// ---------------- level 2: per-bucket LDS histogram + scan + scatter; writes od ----------------
__global__ __launch_bounds__(256) void csr_kernel(const uint* __restrict__ pairs,
                                                  const int* __restrict__ btot,
                                                  int* __restrict__ csr,
                                                  int2* __restrict__ od) {
    int b = blockIdx.x;            // 0..587
    int r = b / NBK;
    int n0 = (b - r * NBK) * BK;   // first node (within relation)
    int cnt = btot[b];
    int base = b * CAPB;
    int t = threadIdx.x;

    __shared__ int hist[BK];
    __shared__ int cur[BK];
    __shared__ int ws[4];
    hist[t] = 0;
    __syncthreads();
    const uint* pp = pairs + base;
    for (int i = t; i < cnt; i += 256) atomicAdd(&hist[pp[i] & 255u], 1);
    __syncthreads();

    int lane = t & 63, w = t >> 6;
    int v = hist[t], s = v;
#pragma unroll
    for (int d = 1; d < 64; d <<= 1) {
        int u = __shfl_up(s, d);
        if (lane >= d) s += u;
    }
    if (lane == 63) ws[w] = s;
    __syncthreads();
    int add = 0;
#pragma unroll
    for (int q = 0; q < 3; ++q)
        if (q < w) add += ws[q];
    int excl = s + add - v;

    int node = n0 + t;
    if (node < NN) od[r * NN + node] = make_int2(base + excl, v);
    cur[t] = excl;
    __syncthreads();

    for (int i = t; i < cnt; i += 256) {
        uint pk = pp[i];
        int pos = atomicAdd(&cur[pk & 255u], 1);
        csr[base + pos] = (int)(pk >> 8);
    }
}

// ---------------- aggregation: one 8-lane group per (rel,node), fp8 gather, fp8 means ----------------
// Lane owns 16 columns (uint4 = 16B row-slice). Masked unroll-8. Output fp8 (16B/lane).
__global__ __launch_bounds__(256) void aggr_kernel(const unsigned char* __restrict__ tb8,
                                                   unsigned char* __restrict__ mean8,
                                                   const int* __restrict__ csr,
                                                   const int2* __restrict__ od) {
    int gtask = (blockIdx.x * 256 + threadIdx.x) >> 3;  // (rel,node) per 8-lane group
    if (gtask >= NR * NN) return;
    int cs = threadIdx.x & 7;
    int2 v2 = od[gtask];
    int base = v2.x, d = v2.y;
    const int* lst = csr + base;
    const unsigned char* tbc = tb8 + cs * 16;

    f32x2 a2[8] = {{0.f, 0.f}, {0.f, 0.f}, {0.f, 0.f}, {0.f, 0.f},
                   {0.f, 0.f}, {0.f, 0.f}, {0.f, 0.f}, {0.f, 0.f}};
    for (int e = 0; e < d; e += 8) {
        uint4 q[8];
#pragma unroll
        for (int k = 0; k < 8; ++k) {
            int ee = e + k;
            int idx = lst[min(ee, d - 1)];
            uint4 v = *(const uint4*)(tbc + (size_t)idx * DH);
            bool ok = ee < d;
            q[k].x = ok ? v.x : 0u;  // fp8 0x00 == +0.0 -> exact no-op add
            q[k].y = ok ? v.y : 0u;
            q[k].z = ok ? v.z : 0u;
            q[k].w = ok ? v.w : 0u;
        }
#pragma unroll
        for (int k = 0; k < 8; ++k) {
            a2[0] = pkadd(a2[0], f8lo(q[k].x));
            a2[1] = pkadd(a2[1], f8hi(q[k].x));
            a2[2] = pkadd(a2[2], f8lo(q[k].y));
            a2[3] = pkadd(a2[3], f8hi(q[k].y));
            a2[4] = pkadd(a2[4], f8lo(q[k].z));
            a2[5] = pkadd(a2[5], f8hi(q[k].z));
            a2[6] = pkadd(a2[6], f8lo(q[k].w));
            a2[7] = pkadd(a2[7], f8hi(q[k].w));
        }
    }
    float inv = 1.f / fmaxf((float)d, 1.f);
    uint4 o;
    o.x = pack4f8(a2[0].x * inv, a2[0].y * inv, a2[1].x * inv, a2[1].y * inv);
    o.y = pack4f8(a2[2].x * inv, a2[2].y * inv, a2[3].x * inv, a2[3].y * inv);
    o.z = pack4f8(a2[4].x * inv, a2[4].y * inv, a2[5].x * inv, a2[5].y * inv);
    o.w = pack4f8(a2[6].x * inv, a2[6].y * inv, a2[7].x * inv, a2[7].y * inv);
    *(uint4*)(mean8 + (size_t)gtask * DH + cs * 16) = o;
}

// ---------------- MFMA GEMM: 64x128 tile, K=512, swapped-operand ----------------
// Mean segments staged from fp8 (cvt -> bf16 via v_perm truncation).
// LAST=false: root from fp32 x; writes h1b (bf16) + h1f8 (fp8 table).
// LAST=true : root from h1b (bf16); fused final linear -> fp32 out.
template <bool LAST>
__global__ __launch_bounds__(256) void gemm_mfma(
    const float* __restrict__ xroot,        // fp32 x (LAST=false)
    const ushort* __restrict__ tbroot,      // bf16 h1b (LAST=true)
    const unsigned char* __restrict__ mean8,// [3][NN][128] fp8 means
    void* __restrict__ h_out,
    unsigned char* __restrict__ h1f8,       // fp8 h1 table out (LAST=false)
    const ushort* __restrict__ Wp,
    const float* __restrict__ bsum,
    const ushort* __restrict__ lWp,
    const float* __restrict__ linb)
{
    __shared__ ushort As[64][136];

    const int t = threadIdx.x, lane = t & 63, w = t >> 6;
    const int l15 = lane & 15, l4 = lane >> 4;
    const int row0 = blockIdx.x * 64;

    f32x4 acc[4][2];
    {
        float4 b0 = *(const float4*)(bsum + (2 * w) * 16 + l4 * 4);
        float4 b1 = *(const float4*)(bsum + (2 * w + 1) * 16 + l4 * 4);
#pragma unroll
        for (int rt = 0; rt < 4; ++rt) {
            acc[rt][0] = f32x4{b0.x, b0.y, b0.z, b0.w};
            acc[rt][1] = f32x4{b1.x, b1.y, b1.z, b1.w};
        }
    }

    for (int seg = 0; seg < 4; ++seg) {
        __syncthreads();
        if (seg < NR) {
            // stage fp8 means: 64 rows x 8 chunks of 16 fp8; 256 threads x 2 iters
#pragma unroll
            for (int i = 0; i < 2; ++i) {
                int q = i * 256 + t;
                int r = q >> 3, c = q & 7;
                int node = row0 + r;
                uint4 o0 = make_uint4(0, 0, 0, 0), o1 = make_uint4(0, 0, 0, 0);
                if (node < NN) {
                    uint4 v = *(const uint4*)(mean8 + ((size_t)seg * NN + node) * DH + c * 16);
                    f32x2 lo, hi;
                    lo = f8lo(v.x); hi = f8hi(v.x);
                    o0.x = pk2t(lo.x, lo.y); o0.y = pk2t(hi.x, hi.y);
                    lo = f8lo(v.y); hi = f8hi(v.y);
                    o0.z = pk2t(lo.x, lo.y); o0.w = pk2t(hi.x, hi.y);
                    lo = f8lo(v.z); hi = f8hi(v.z);
                    o1.x = pk2t(lo.x, lo.y); o1.y = pk2t(hi.x, hi.y);
                    lo = f8lo(v.w); hi = f8hi(v.w);
                    o1.z = pk2t(lo.x, lo.y); o1.w = pk2t(hi.x, hi.y);
                }
                *(uint4*)(&As[r][c * 16]) = o0;
                *(uint4*)(&As[r][c * 16 + 8]) = o1;
            }
        } else {
            // root segment: 64 rows x 16 chunks of 8 bf16; 256 threads x 4 iters
#pragma unroll
            for (int i = 0; i < 4; ++i) {
                int q = i * 256 + t;
                int r = q >> 4, c = q & 15;
                int node = row0 + r;
                uint4 v = make_uint4(0, 0, 0, 0);
                if (node < NN) {
                    if constexpr (!LAST) {
                        float4 f0 = *(const float4*)(xroot + (size_t)node * DH + c * 8);
                        float4 f1 = *(const float4*)(xroot + (size_t)node * DH + c * 8 + 4);
                        v.x = pack2(f0.x, f0.y);
                        v.y = pack2(f0.z, f0.w);
                        v.z = pack2(f1.x, f1.y);
                        v.w = pack2(f1.z, f1.w);
                    } else {
                        v = *(const uint4*)(tbroot + (size_t)node * DH + c * 8);
                    }
                }
                *(uint4*)(&As[r][c * 8]) = v;
            }
        }
        __syncthreads();
        const ushort* wseg = Wp + (size_t)seg * 32768;
#pragma unroll
        for (int kc = 0; kc < 4; ++kc) {
            const ushort* wkc = wseg + kc * 8192;
            short8 bh0 = *(const short8*)(wkc + (2 * w) * 1024 + lane * 8);
            short8 bl0 = *(const short8*)(wkc + (2 * w) * 1024 + 512 + lane * 8);
            short8 bh1 = *(const short8*)(wkc + (2 * w + 1) * 1024 + lane * 8);
            short8 bl1 = *(const short8*)(wkc + (2 * w + 1) * 1024 + 512 + lane * 8);
#pragma unroll
            for (int rt = 0; rt < 4; ++rt) {
                short8 a = *(const short8*)(&As[rt * 16 + l15][kc * 32 + l4 * 8]);
                acc[rt][0] = __builtin_amdgcn_mfma_f32_16x16x32_bf16(bh0, a, acc[rt][0], 0, 0, 0);
                acc[rt][0] = __builtin_amdgcn_mfma_f32_16x16x32_bf16(bl0, a, acc[rt][0], 0, 0, 0);
                acc[rt][1] = __builtin_amdgcn_mfma_f32_16x16x32_bf16(bh1, a, acc[rt][1], 0, 0, 0);
                acc[rt][1] = __builtin_amdgcn_mfma_f32_16x16x32_bf16(bl1, a, acc[rt][1], 0, 0, 0);
            }
        }
    }

    if constexpr (!LAST) {
        ushort* hb = (ushort*)h_out;
#pragma unroll
        for (int rt = 0; rt < 4; ++rt) {
            int node = row0 + rt * 16 + l15;
            if (node < NN) {
#pragma unroll
                for (int j = 0; j < 2; ++j) {
                    int c0 = (2 * w + j) * 16 + l4 * 4;
                    float r0 = fmaxf(acc[rt][j][0], 0.f);
                    float r1 = fmaxf(acc[rt][j][1], 0.f);
                    float r2 = fmaxf(acc[rt][j][2], 0.f);
                    float r3 = fmaxf(acc[rt][j][3], 0.f);
                    uint2 o;
                    o.x = pack2(r0, r1);
                    o.y = pack2(r2, r3);
                    *(uint2*)(hb + (size_t)node * DH + c0) = o;
                    *(uint*)(h1f8 + (size_t)node * DH + c0) = pack4f8(r0, r1, r2, r3);
                }
            }
        }
    } else {
        __syncthreads();
#pragma unroll
        for (int rt = 0; rt < 4; ++rt) {
            int rl = rt * 16 + l15;
#pragma unroll
            for (int j = 0; j < 2; ++j) {
                int c0 = (2 * w + j) * 16 + l4 * 4;
                uint2 o;
                o.x = pack2(fmaxf(acc[rt][j][0], 0.f), fmaxf(acc[rt][j][1], 0.f));
                o.y = pack2(fmaxf(acc[rt][j][2], 0.f), fmaxf(acc[rt][j][3], 0.f));
                *(uint2*)(&As[rl][c0]) = o;
            }
        }
        __syncthreads();
        f32x4 acc2[2];
        {
            float4 c0 = *(const float4*)(linb + l4 * 4);
            float4 c1 = *(const float4*)(linb + 16 + l4 * 4);
            acc2[0] = f32x4{c0.x, c0.y, c0.z, c0.w};
            acc2[1] = f32x4{c1.x, c1.y, c1.z, c1.w};
        }
#pragma unroll
        for (int kc = 0; kc < 4; ++kc) {
            short8 a = *(const short8*)(&As[w * 16 + l15][kc * 32 + l4 * 8]);
#pragma unroll
            for (int j = 0; j < 2; ++j) {
                short8 bh = *(const short8*)(lWp + (kc * 2 + j) * 1024 + lane * 8);
                short8 bl = *(const short8*)(lWp + (kc * 2 + j) * 1024 + 512 + lane * 8);
                acc2[j] = __builtin_amdgcn_mfma_f32_16x16x32_bf16(bh, a, acc2[j], 0, 0, 0);
                acc2[j] = __builtin_amdgcn_mfma_f32_16x16x32_bf16(bl, a, acc2[j], 0, 0, 0);
            }
        }
        float* outp = (float*)h_out;
        int node = row0 + w * 16 + l15;
        if (node < NN) {
#pragma unroll
            for (int j = 0; j < 2; ++j) {
                *(f32x4*)(outp + (size_t)node * 32 + j * 16 + l4 * 4) = acc2[j];
            }
        }
    }
}

extern "C" void kernel_launch(void* const* d_in, const int* in_sizes, int n_in,
                              void* d_out, int out_size, void* d_ws, size_t ws_size,
                              hipStream_t stream) {
    const float* x = (const float*)d_in[0];
    const int* ei = (const int*)d_in[1];
    const float* Wn = (const float*)d_in[2];
    const float* Wr = (const float*)d_in[3];
    const float* bc = (const float*)d_in[4];
    const float* linW = (const float*)d_in[5];
    const float* linb = (const float*)d_in[6];
    float* out = (float*)d_out;

    char* p = (char*)d_ws;
    int* gcnt = (int*)p;     p += (size_t)NCH * NBT * 4;      // 1.2 MB
    int* gbase = (int*)p;    p += (size_t)NCH * NBT * 4;      // 1.2 MB
    int* btot = (int*)p;     p += 4096;
    int2* od = (int2*)p;     p += (size_t)NR * NN * 8;        // 1.2 MB
    int* csr = (int*)p;      p += (size_t)NBT * CAPB * 4;     // 9.6 MB
    ushort* Wpack = (ushort*)p; p += (size_t)264 * 1024 * 2;  // 540 KB
    float* bsum = (float*)p; p += 4096;
    unsigned char* f8tab = (unsigned char*)p; p += (size_t)NN * DH;  // 6.4 MB (x-fp8, then h1-fp8)
    ushort* h1b = (ushort*)p; p += (size_t)NN * DH * 2;       // 12.8 MB
    unsigned char* mean8 = (unsigned char*)p; p += (size_t)NR * NN * DH;  // 19.2 MB
    uint* pairs = (uint*)mean8;  // alias (7.7 MB): consumed by csr_kernel
                                 // before any aggr writes mean8

    prep_hist<<<NCH + 6251 + 66 + 1, 256, 0, stream>>>(x, ei, Wn, Wr, bc, linW,
                                                       f8tab, Wpack, bsum, gcnt);
    cscan_kernel<<<NBT, 256, 0, stream>>>(gcnt, gbase, btot);
    scatter_kernel<<<NCH, 256, 0, stream>>>(ei, gbase, pairs);
    csr_kernel<<<NBT, 256, 0, stream>>>(pairs, btot, csr, od);

    int lb = (NN + 63) / 64;              // 782
    int ag = (NR * NN * 8 + 255) / 256;   // 4688 blocks (8 lanes per task)

    // layer 1: gather from x-fp8, root from x-fp32; writes h1b + h1-fp8 (into f8tab)
    aggr_kernel<<<ag, 256, 0, stream>>>(f8tab, mean8, csr, od);
    gemm_mfma<false><<<lb, 256, 0, stream>>>(x, nullptr, mean8, h1b, f8tab,
                                             Wpack, bsum, nullptr, nullptr);
    // layer 2: gather from h1-fp8, root from h1b; fused final linear
    aggr_kernel<<<ag, 256, 0, stream>>>(f8tab, mean8, csr, od);
    gemm_mfma<true><<<lb, 256, 0, stream>>>(nullptr, h1b, mean8, out, nullptr,
                                            Wpack + (size_t)128 * 1024, bsum + DH,
                                            Wpack + (size_t)256 * 1024, linb);
}